// Round 9
// baseline (1107.249 us; speedup 1.0000x reference)
//
#include <hip/hip_runtime.h>
#include <hip/hip_bf16.h>
#include <math.h>

#define BSZ   1024
#define TLEN  320
#define EEGC  64
#define GEOC  18
#define ECH   512    // 64*8
#define GCH   144    // 18*8
#define HID   32
#define KW    32
#define TT    32
#define NT    (TLEN/TT)   // 10

// ---- workspace layout (float offsets) ----
#define OFF_ENC  0
#define OFF_MOD  (OFF_ENC + BSZ*TLEN*HID)
#define OFF_DP   (OFF_MOD + BSZ*TLEN*HID)
#define OFF_CWE  (OFF_DP + BSZ*HID*10)           // conv weights eeg [c][k] (A1-folded)
#define OFF_CWG  (OFF_CWE + ECH*KW)
#define OFF_DWE  (OFF_CWG + GCH*KW)              // dense weights eeg [c][h] (A2-folded)
#define OFF_DWG  (OFF_DWE + ECH*HID)
#define OFF_BTE  (OFF_DWG + GCH*HID)
#define OFF_BTG  (OFF_BTE + HID)
#define OFF_GAM  (OFF_BTG + HID)

struct P29 { const float* p[29]; };
// 0 ecw 1 ecb 2 e1s 3 e1b 4 e1m 5 e1v 6 edw 7 edb 8 e2s 9 e2b 10 e2m 11 e2v
// 12 gcw 13 gcb 14 g1s 15 g1b 16 g1m 17 g1v 18 gdw 19 gdb 20 g2s 21 g2b 22 g2m 23 g2v
// 24 gamma 25 fc1w 26 fc1b 27 fc2w 28 fc2b

// ============================================================
// prep v3 (r8 form). Unchanged.
// ============================================================
__global__ __launch_bounds__(256) void prep_kernel(P29 P, float* __restrict__ ws)
{
    __shared__ float pse[8][32];
    __shared__ float psg[8][32];
    const int tid = threadIdx.x;
    const int gid = blockIdx.x * 256 + tid;
    const int gstride = 33 * 256;
    float* convW_e = ws + OFF_CWE;
    float* convW_g = ws + OFF_CWG;
    float* dW_e    = ws + OFF_DWE;
    float* dW_g    = ws + OFF_DWG;

    for (int i = gid; i < ECH * KW; i += gstride) {
        int c = i >> 5, k = i & 31;
        float A1 = P.p[2][c] * rsqrtf(P.p[5][c] + 1e-5f);
        convW_e[c * KW + k] = P.p[0][(size_t)k * ECH + c] * A1;
    }
    for (int i = gid; i < GCH * KW; i += gstride) {
        int c = i >> 5, k = i & 31;
        float A1 = P.p[14][c] * rsqrtf(P.p[17][c] + 1e-5f);
        convW_g[c * KW + k] = P.p[12][(size_t)k * GCH + c] * A1;
    }
    for (int i = gid; i < ECH * HID; i += gstride) {
        int h = i & 31;
        float A2 = P.p[8][h] * rsqrtf(P.p[11][h] + 1e-5f);
        dW_e[i] = P.p[6][i] * A2;
    }
    for (int i = gid; i < GCH * HID; i += gstride) {
        int h = i & 31;
        float A2 = P.p[20][h] * rsqrtf(P.p[23][h] + 1e-5f);
        dW_g[i] = P.p[18][i] * A2;
    }
    for (int i = gid; i < HID; i += gstride) ws[OFF_GAM + i] = P.p[24][i];

    if (blockIdx.x == 0) {
        {
            const int h = tid & 31, part = tid >> 5;
            float s = 0.f;
            for (int c = part * 64; c < part * 64 + 64; ++c) {
                float A1 = P.p[2][c] * rsqrtf(P.p[5][c] + 1e-5f);
                float C1 = (P.p[1][c] - P.p[4][c]) * A1 + P.p[3][c];
                s += C1 * P.p[6][(size_t)c * HID + h];
            }
            pse[part][h] = s;
            float sg = 0.f;
            for (int c = part * 18; c < part * 18 + 18; ++c) {
                float A1 = P.p[14][c] * rsqrtf(P.p[17][c] + 1e-5f);
                float C1 = (P.p[13][c] - P.p[16][c]) * A1 + P.p[15][c];
                sg += C1 * P.p[18][(size_t)c * HID + h];
            }
            psg[part][h] = sg;
        }
        __syncthreads();
        if (tid < HID) {
            int h = tid;
            float A2 = P.p[8][h] * rsqrtf(P.p[11][h] + 1e-5f);
            float s = pse[0][h] + pse[1][h] + pse[2][h] + pse[3][h]
                    + pse[4][h] + pse[5][h] + pse[6][h] + pse[7][h];
            ws[OFF_BTE + h] = A2 * (s + P.p[7][h] - P.p[10][h]) + P.p[9][h];
        } else if (tid >= 64 && tid < 64 + HID) {
            int h = tid - 64;
            float A2 = P.p[20][h] * rsqrtf(P.p[23][h] + 1e-5f);
            float s = psg[0][h] + psg[1][h] + psg[2][h] + psg[3][h]
                    + psg[4][h] + psg[5][h] + psg[6][h] + psg[7][h];
            ws[OFF_BTG + h] = A2 * (s + P.p[19][h] - P.p[22][h]) + P.p[21][h];
        }
    }
}

// conv inner: stream 12 b128 chunks of the 47-wide window with 1-deep
// lookahead; per-t FMA order is j (=t+k) ascending == k ascending:
// bit-identical to the scalar version.
__device__ __forceinline__ void conv_stream(const float4* __restrict__ xp4,
                                            const float* __restrict__ w,
                                            float* __restrict__ acc)
{
    float4 cur = xp4[0];
    #pragma unroll
    for (int j4 = 0; j4 < 12; ++j4) {
        float4 nxt = (j4 < 11) ? xp4[j4 + 1] : cur;
        #pragma unroll
        for (int i2 = 0; i2 < 4; ++i2) {
            const int i = j4 * 4 + i2;
            const float xv = (i2 == 0) ? cur.x : (i2 == 1) ? cur.y
                           : (i2 == 2) ? cur.z : cur.w;
            const int tlo = (i - 31 > 0) ? (i - 31) : 0;
            const int thi = (i < 15) ? i : 15;
            #pragma unroll
            for (int t = tlo; t <= thi; ++t)
                acc[t] = fmaf(xv, w[i - t], acc[t]);
        }
        cur = nxt;
    }
}

__device__ __forceinline__ void geo_conv_unit(const float* __restrict__ convW,
                                              const float* __restrict__ xsT,
                                              float* __restrict__ cz,
                                              int c, int th)
{
    float w[KW];
    const float4* wp4 = (const float4*)(convW + c * KW);
    #pragma unroll
    for (int k4 = 0; k4 < 8; ++k4) {
        float4 v = wp4[k4];
        w[4*k4+0]=v.x; w[4*k4+1]=v.y; w[4*k4+2]=v.z; w[4*k4+3]=v.w;
    }
    float acc[16];
    #pragma unroll
    for (int t = 0; t < 16; ++t) acc[t] = 0.f;
    conv_stream((const float4*)(xsT + (c >> 3) * 68 + th * 16), w, acc);
    float4* czp = (float4*)(cz + c * 36 + th * 16);
    czp[0] = make_float4(acc[0],  acc[1],  acc[2],  acc[3]);
    czp[1] = make_float4(acc[4],  acc[5],  acc[6],  acc[7]);
    czp[2] = make_float4(acc[8],  acc[9],  acc[10], acc[11]);
    czp[3] = make_float4(acc[12], acc[13], acc[14], acc[15]);
}

// ============================================================
// Merged path kernel (r8 base). EEG change: per-phase staging moved
// from its own barrier-bracketed slot into the dense region — issue
// the global load for phase ph+1 right after the conv barrier, run
// dense (≈2000 cyc issue) to hide the ~500-cyc L3 latency, write
// xsT after dense, barrier. 12 -> 9 barriers/block, stage latency
// hidden. sv is live across DENSE only (low-pressure region, ~54
// live) — NOT across conv (r3's cliff was sv live across conv's
// w[32]+acc[16] peak). Tripwire: FETCH >> 99 MB = demotion cliff ->
// revert to r8 transient staging.
// GEO change: dense loop gets eeg's wvb[4]/cvb[2] pipelined loads
// (was unpipelined unroll-2; dW_g is L2-resident, ~200 cyc exposed).
// FMA order ci-ascending unchanged -> bit-identical.
// ============================================================
__global__ __launch_bounds__(256)
void path_both(const float* __restrict__ xe, const float* __restrict__ xg,
               float* __restrict__ ws)
{
    __shared__ __align__(16) float smem[6408];

    const int b   = blockIdx.y;
    const int tid = threadIdx.x;

    if (blockIdx.x < NT) {
        // ================= EEG =================
        const int t0 = blockIdx.x * TT;
        float* xsT = smem;            // 16*68 = 1088
        float* cz  = smem + 1088;     // 128*36 = 4608
        const float* convW = ws + OFF_CWE;
        const float* dW    = ws + OFF_DWE;
        float* enc         = ws + OFF_ENC;

        const float* xb = xe + (size_t)b * (TLEN * EEGC);

        const int tg = tid & 7, hg = (tid >> 3) & 7, q = tid >> 6;
        const int c_loc = tid & 127, th = tid >> 7;
        float a00=0,a01=0,a02=0,a03=0, a10=0,a11=0,a12=0,a13=0;
        float a20=0,a21=0,a22=0,a23=0, a30=0,a31=0,a32=0,a33=0;

        // ---- prologue: stage phase 0 (transient) ----
        if (tid < 252) {
            const int sj = tid >> 2, sc4 = tid & 3;
            const int st = t0 - 15 + sj;
            float4 sv = make_float4(0.f, 0.f, 0.f, 0.f);
            if (st >= 0 && st < TLEN)
                sv = *(const float4*)(xb + (size_t)st * EEGC + sc4 * 4);
            float* p = &xsT[(sc4 * 4) * 68 + sj];
            p[0] = sv.x; p[68] = sv.y; p[136] = sv.z; p[204] = sv.w;
        }
        __syncthreads();

        #pragma unroll 1
        for (int ph = 0; ph < 4; ++ph) {
            // ---- conv: channel c = ph*128 + c_loc ----
            {
                const int c   = ph * 128 + c_loc;
                const int chl = c_loc >> 3;
                float w[KW];
                const float4* wp4 = (const float4*)(convW + c * KW);
                #pragma unroll
                for (int k4 = 0; k4 < 8; ++k4) {
                    float4 v = wp4[k4];
                    w[4*k4+0]=v.x; w[4*k4+1]=v.y; w[4*k4+2]=v.z; w[4*k4+3]=v.w;
                }
                float acc[16];
                #pragma unroll
                for (int t = 0; t < 16; ++t) acc[t] = 0.f;
                conv_stream((const float4*)(&xsT[chl * 68 + th * 16]), w, acc);
                float4* czp = (float4*)(cz + c_loc * 36 + th * 16);
                czp[0] = make_float4(acc[0],  acc[1],  acc[2],  acc[3]);
                czp[1] = make_float4(acc[4],  acc[5],  acc[6],  acc[7]);
                czp[2] = make_float4(acc[8],  acc[9],  acc[10], acc[11]);
                czp[3] = make_float4(acc[12], acc[13], acc[14], acc[15]);
            }
            __syncthreads();   // cz ready for dense; xsT free for restage

            // ---- issue next phase's stage load (hides under dense) ----
            float4 sv = make_float4(0.f, 0.f, 0.f, 0.f);
            if (ph < 3 && tid < 252) {
                const int sj = tid >> 2, sc4 = tid & 3;
                const int st = t0 - 15 + sj;
                if (st >= 0 && st < TLEN)
                    sv = *(const float4*)(xb + (size_t)st * EEGC + (ph + 1) * 16 + sc4 * 4);
            }

            // ---- dense partial: my wave's 32-c chunk, pipelined loads ----
            {
                const float* dWh = dW + (size_t)(ph * 128 + q * 32) * HID + hg * 4;
                const float* czb = cz + (q * 32) * 36 + tg * 4;
                float4 wvb[4], cvb[2];
                wvb[0] = *(const float4*)(dWh + 0 * HID);
                wvb[1] = *(const float4*)(dWh + 1 * HID);
                wvb[2] = *(const float4*)(dWh + 2 * HID);
                wvb[3] = *(const float4*)(dWh + 3 * HID);
                cvb[0] = *(const float4*)(czb + 0 * 36);
                cvb[1] = *(const float4*)(czb + 1 * 36);
                #pragma unroll
                for (int ci = 0; ci < 32; ++ci) {
                    float4 cv = cvb[ci & 1];
                    float4 wv = wvb[ci & 3];
                    if (ci + 2 < 32) cvb[ci & 1] = *(const float4*)(czb + (ci + 2) * 36);
                    if (ci + 4 < 32) wvb[ci & 3] = *(const float4*)(dWh + (ci + 4) * HID);
                    a00 = fmaf(cv.x, wv.x, a00); a01 = fmaf(cv.x, wv.y, a01);
                    a02 = fmaf(cv.x, wv.z, a02); a03 = fmaf(cv.x, wv.w, a03);
                    a10 = fmaf(cv.y, wv.x, a10); a11 = fmaf(cv.y, wv.y, a11);
                    a12 = fmaf(cv.y, wv.z, a12); a13 = fmaf(cv.y, wv.w, a13);
                    a20 = fmaf(cv.z, wv.x, a20); a21 = fmaf(cv.z, wv.y, a21);
                    a22 = fmaf(cv.z, wv.z, a22); a23 = fmaf(cv.z, wv.w, a23);
                    a30 = fmaf(cv.w, wv.x, a30); a31 = fmaf(cv.w, wv.y, a31);
                    a32 = fmaf(cv.w, wv.z, a32); a33 = fmaf(cv.w, wv.w, a33);
                }
            }

            // ---- write staged slice (xsT disjoint from dense's cz) ----
            if (ph < 3 && tid < 252) {
                const int sj = tid >> 2, sc4 = tid & 3;
                float* p = &xsT[(sc4 * 4) * 68 + sj];
                p[0] = sv.x; p[68] = sv.y; p[136] = sv.z; p[204] = sv.w;
            }
            __syncthreads();   // xsT ready for conv(ph+1); cz free
        }

        // ---- 4-chunk reduction (stash stride 16, XOR group swizzle) ----
        float* stash = cz - 1088 + 1088;  // czs region
        stash = smem;                     // 256*16 = 4096 floats
        {
            const int s = (tid >> 1) & 3;
            float4* sp = (float4*)(stash + tid * 16);
            sp[s ^ 0] = make_float4(a00,a01,a02,a03);
            sp[s ^ 1] = make_float4(a10,a11,a12,a13);
            sp[s ^ 2] = make_float4(a20,a21,a22,a23);
            sp[s ^ 3] = make_float4(a30,a31,a32,a33);
        }
        __syncthreads();
        {
            const int t = tid >> 3, hq = tid & 7;
            const int pg = (t & 3) ^ (t >> 3);
            float4 v = make_float4(0.f,0.f,0.f,0.f);
            #pragma unroll
            for (int qq = 0; qq < 4; ++qq) {
                const int partner = qq * 64 + hq * 8 + (t >> 2);
                float4 s = *(const float4*)(stash + partner * 16 + pg * 4);
                v.x += s.x; v.y += s.y; v.z += s.z; v.w += s.w;
            }
            float4 bias = *(const float4*)(ws + OFF_BTE + hq * 4);
            v.x = fmaxf(v.x + bias.x, 0.f);
            v.y = fmaxf(v.y + bias.y, 0.f);
            v.z = fmaxf(v.z + bias.z, 0.f);
            v.w = fmaxf(v.w + bias.w, 0.f);
            *(float4*)(enc + ((size_t)(b * TLEN + t0 + t)) * HID + hq * 4) = v;
        }
    } else {
        // ================= GEO =================
        const int t0 = (blockIdx.x - NT) * TT;
        float* xsT = smem;            // 18*68 = 1224
        float* cz  = smem + 1224;     // 144*36 = 5184
        const float* convW = ws + OFF_CWG;
        const float* dW    = ws + OFF_DWG;
        float* mod         = ws + OFF_MOD;

        const float* xb = xg + (size_t)b * (TLEN * GEOC);
        for (int i = tid; i < 63 * GEOC; i += 256) {
            int j = i / GEOC, ch = i - j * GEOC;
            int t = t0 - 15 + j;
            xsT[ch * 68 + j] = (t >= 0 && t < TLEN) ? xb[(size_t)t * GEOC + ch] : 0.f;
        }
        __syncthreads();

        geo_conv_unit(convW, xsT, cz, tid >> 1, tid & 1);
        if (tid < 32)
            geo_conv_unit(convW, xsT, cz, 128 + (tid >> 1), tid & 1);
        __syncthreads();

        const int tg = tid & 7, hg = (tid >> 3) & 7, q = tid >> 6;
        float a00=0,a01=0,a02=0,a03=0, a10=0,a11=0,a12=0,a13=0;
        float a20=0,a21=0,a22=0,a23=0, a30=0,a31=0,a32=0,a33=0;
        {
            const float* dWh = dW + (size_t)(q * 36) * HID + hg * 4;
            const float* czb = cz + (q * 36) * 36 + tg * 4;
            float4 wvb[4], cvb[2];
            wvb[0] = *(const float4*)(dWh + 0 * HID);
            wvb[1] = *(const float4*)(dWh + 1 * HID);
            wvb[2] = *(const float4*)(dWh + 2 * HID);
            wvb[3] = *(const float4*)(dWh + 3 * HID);
            cvb[0] = *(const float4*)(czb + 0 * 36);
            cvb[1] = *(const float4*)(czb + 1 * 36);
            #pragma unroll
            for (int ci = 0; ci < 36; ++ci) {
                float4 cv = cvb[ci & 1];
                float4 wv = wvb[ci & 3];
                if (ci + 2 < 36) cvb[ci & 1] = *(const float4*)(czb + (ci + 2) * 36);
                if (ci + 4 < 36) wvb[ci & 3] = *(const float4*)(dWh + (ci + 4) * HID);
                a00 = fmaf(cv.x, wv.x, a00); a01 = fmaf(cv.x, wv.y, a01);
                a02 = fmaf(cv.x, wv.z, a02); a03 = fmaf(cv.x, wv.w, a03);
                a10 = fmaf(cv.y, wv.x, a10); a11 = fmaf(cv.y, wv.y, a11);
                a12 = fmaf(cv.y, wv.z, a12); a13 = fmaf(cv.y, wv.w, a13);
                a20 = fmaf(cv.z, wv.x, a20); a21 = fmaf(cv.z, wv.y, a21);
                a22 = fmaf(cv.z, wv.z, a22); a23 = fmaf(cv.z, wv.w, a23);
                a30 = fmaf(cv.w, wv.x, a30); a31 = fmaf(cv.w, wv.y, a31);
                a32 = fmaf(cv.w, wv.z, a32); a33 = fmaf(cv.w, wv.w, a33);
            }
        }
        __syncthreads();
        float* stash = cz;
        {
            float4* sp = (float4*)(stash + tid * 20);
            sp[0] = make_float4(a00,a01,a02,a03);
            sp[1] = make_float4(a10,a11,a12,a13);
            sp[2] = make_float4(a20,a21,a22,a23);
            sp[3] = make_float4(a30,a31,a32,a33);
        }
        __syncthreads();
        {
            const int t = tid >> 3, hq = tid & 7;
            float4 v = make_float4(0.f,0.f,0.f,0.f);
            #pragma unroll
            for (int qq = 0; qq < 4; ++qq) {
                const int partner = qq * 64 + hq * 8 + (t >> 2);
                float4 s = *(const float4*)(stash + partner * 20 + (t & 3) * 4);
                v.x += s.x; v.y += s.y; v.z += s.z; v.w += s.w;
            }
            float4 bias = *(const float4*)(ws + OFF_BTG + hq * 4);
            v.x = 1.f / (1.f + expf(-(v.x + bias.x)));
            v.y = 1.f / (1.f + expf(-(v.y + bias.y)));
            v.z = 1.f / (1.f + expf(-(v.z + bias.z)));
            v.w = 1.f / (1.f + expf(-(v.w + bias.w)));
            *(float4*)(mod + ((size_t)(b * TLEN + t0 + t)) * HID + hq * 4) = v;
        }
    }
}

// ============================================================
// Fused scan+head (r7/r8 form). Unchanged.
// ============================================================
#define SSTEP(CE, CG) { \
    const float ce = (CE), cg = (CG); \
    m1 = 0.9f * m1 + ce; float s1 = ((m1 - 0.7f) >= 0.f) ? 1.f : 0.f; m1 = m1 * (1.f - s1); \
    m2 = 0.8f * m2 + ce; float s2 = ((m2 - 0.5f) >= 0.f) ? 1.f : 0.f; m2 = m2 * (1.f - s2); \
    m3 = 0.6f * m3 + ce; float s3 = ((m3 - 0.3f) >= 0.f) ? 1.f : 0.f; m3 = m3 * (1.f - s3); \
    const float hr = (s1 + s2 + s3) / 3.0f; \
    eta = 0.36f * eta + 0.64f * prev; \
    const float theta = 0.5f + 1.8f * eta - g * cg; \
    ma = 0.8f * ma + hr; \
    const float sa = ((ma - theta) >= 0.f) ? 1.f : 0.f; \
    ma = ma * (1.f - sa); \
    mli = 0.9f * mli + sa; \
    prev = sa; }

__global__ __launch_bounds__(128) void scan_head_kernel(
    float* __restrict__ ws,
    const float* __restrict__ f1w, const float* __restrict__ f1b,
    const float* __restrict__ f2w, const float* __restrict__ f2b,
    float* __restrict__ out)
{
    __shared__ __align__(16) float dps[4][320];
    __shared__ float act[4][128];
    const int tid = threadIdx.x;
    const int grp = tid >> 5, h = tid & 31;
    const int b = blockIdx.x * 4 + grp;

    {
        const float g = ws[OFF_GAM + h];
        const float* pe = ws + OFF_ENC + (size_t)b * TLEN * HID + h;
        const float* pg = ws + OFF_MOD + (size_t)b * TLEN * HID + h;
        float* dpp = &dps[grp][h * 10];

        float m1 = 0.f, m2 = 0.f, m3 = 0.f, ma = 0.f, eta = 0.f, mli = 0.f, prev = 0.f;
        float acc_lo = 0.f, acc_hi = 0.f;
        float ceA[16], cgA[16], ceB[16], cgB[16];

        #pragma unroll
        for (int i = 0; i < 16; ++i) { ceA[i] = pe[i * HID]; cgA[i] = pg[i * HID]; }

        #pragma unroll 1
        for (int ch = 0; ch < 20; ch += 2) {
            const int baseB = (ch + 1) * 16;
            #pragma unroll
            for (int i = 0; i < 16; ++i) {
                ceB[i] = pe[(baseB + i) * HID];
                cgB[i] = pg[(baseB + i) * HID];
            }
            #pragma unroll
            for (int i = 0; i < 16; ++i) {
                SSTEP(ceA[i], cgA[i]);
                acc_lo += mli;
            }
            if (ch + 2 < 20) {
                const int baseA = (ch + 2) * 16;
                #pragma unroll
                for (int i = 0; i < 16; ++i) {
                    ceA[i] = pe[(baseA + i) * HID];
                    cgA[i] = pg[(baseA + i) * HID];
                }
            }
            #pragma unroll
            for (int i = 0; i < 16; ++i) {
                SSTEP(ceB[i], cgB[i]);
                acc_hi += mli;
            }
            dpp[ch >> 1] = acc_hi * (1.f / 16.f) - acc_lo * (1.f / 16.f);
            acc_lo = 0.f; acc_hi = 0.f;
        }
    }
    __syncthreads();

    {
        const int j = tid;
        #pragma unroll 1
        for (int gb = 0; gb < 4; ++gb) {
            const float* dpb = dps[gb];
            float a0 = 0.f, a1 = 0.f, a2 = 0.f, a3 = 0.f;
            #pragma unroll 4
            for (int i = 0; i < 320; i += 4) {
                a0 = fmaf(dpb[i + 0], f1w[(i + 0) * 128 + j], a0);
                a1 = fmaf(dpb[i + 1], f1w[(i + 1) * 128 + j], a1);
                a2 = fmaf(dpb[i + 2], f1w[(i + 2) * 128 + j], a2);
                a3 = fmaf(dpb[i + 3], f1w[(i + 3) * 128 + j], a3);
            }
            float a = f1b[j] + ((a0 + a1) + (a2 + a3));
            act[gb][j] = (a > 0.f) ? a : expm1f(a);   // ELU, alpha=1
        }
    }
    __syncthreads();

    if (tid < 16) {
        const int gb = tid >> 2, j = tid & 3;
        float o = f2b[j];
        for (int jj = 0; jj < 128; ++jj)
            o = fmaf(act[gb][jj], f2w[jj * 4 + j], o);
        out[(blockIdx.x * 4 + gb) * 4 + j] = o;
    }
}

// ============================================================
extern "C" void kernel_launch(void* const* d_in, const int* in_sizes, int n_in,
                              void* d_out, int out_size, void* d_ws, size_t ws_size,
                              hipStream_t stream)
{
    float* ws = (float*)d_ws;

    P29 P;
    for (int k = 0; k < 29; ++k) P.p[k] = (const float*)d_in[k + 2];
    prep_kernel<<<33, 256, 0, stream>>>(P, ws);

    path_both<<<dim3(2 * NT, BSZ), 256, 0, stream>>>(
        (const float*)d_in[0], (const float*)d_in[1], ws);

    scan_head_kernel<<<BSZ / 4, 128, 0, stream>>>(
        ws, (const float*)d_in[27], (const float*)d_in[28],
        (const float*)d_in[29], (const float*)d_in[30], (float*)d_out);
}

// Round 10
// 706.477 us; speedup vs baseline: 1.5673x; 1.5673x over previous
//
#include <hip/hip_runtime.h>
#include <hip/hip_bf16.h>
#include <math.h>

#define BSZ   1024
#define TLEN  320
#define EEGC  64
#define GEOC  18
#define ECH   512    // 64*8
#define GCH   144    // 18*8
#define HID   32
#define KW    32
#define TT    32
#define NT    (TLEN/TT)   // 10

// ---- workspace layout (float offsets) ----
#define OFF_ENC  0
#define OFF_MOD  (OFF_ENC + BSZ*TLEN*HID)
#define OFF_DP   (OFF_MOD + BSZ*TLEN*HID)
#define OFF_CWE  (OFF_DP + BSZ*HID*10)           // conv weights eeg [c][k] (A1-folded)
#define OFF_CWG  (OFF_CWE + ECH*KW)
#define OFF_DWE  (OFF_CWG + GCH*KW)              // dense weights eeg [c][h] (A2-folded)
#define OFF_DWG  (OFF_DWE + ECH*HID)
#define OFF_BTE  (OFF_DWG + GCH*HID)
#define OFF_BTG  (OFF_BTE + HID)
#define OFF_GAM  (OFF_BTG + HID)

struct P29 { const float* p[29]; };
// 0 ecw 1 ecb 2 e1s 3 e1b 4 e1m 5 e1v 6 edw 7 edb 8 e2s 9 e2b 10 e2m 11 e2v
// 12 gcw 13 gcb 14 g1s 15 g1b 16 g1m 17 g1v 18 gdw 19 gdb 20 g2s 21 g2b 22 g2m 23 g2v
// 24 gamma 25 fc1w 26 fc1b 27 fc2w 28 fc2b

// ============================================================
// prep v3 (r8 form): elementwise weight folds spread over 33 blocks;
// block 0 does the bias reductions + gamma. Bit-identical arithmetic.
// ============================================================
__global__ __launch_bounds__(256) void prep_kernel(P29 P, float* __restrict__ ws)
{
    __shared__ float pse[8][32];
    __shared__ float psg[8][32];
    const int tid = threadIdx.x;
    const int gid = blockIdx.x * 256 + tid;
    const int gstride = 33 * 256;
    float* convW_e = ws + OFF_CWE;
    float* convW_g = ws + OFF_CWG;
    float* dW_e    = ws + OFF_DWE;
    float* dW_g    = ws + OFF_DWG;

    for (int i = gid; i < ECH * KW; i += gstride) {
        int c = i >> 5, k = i & 31;
        float A1 = P.p[2][c] * rsqrtf(P.p[5][c] + 1e-5f);
        convW_e[c * KW + k] = P.p[0][(size_t)k * ECH + c] * A1;
    }
    for (int i = gid; i < GCH * KW; i += gstride) {
        int c = i >> 5, k = i & 31;
        float A1 = P.p[14][c] * rsqrtf(P.p[17][c] + 1e-5f);
        convW_g[c * KW + k] = P.p[12][(size_t)k * GCH + c] * A1;
    }
    for (int i = gid; i < ECH * HID; i += gstride) {
        int h = i & 31;
        float A2 = P.p[8][h] * rsqrtf(P.p[11][h] + 1e-5f);
        dW_e[i] = P.p[6][i] * A2;
    }
    for (int i = gid; i < GCH * HID; i += gstride) {
        int h = i & 31;
        float A2 = P.p[20][h] * rsqrtf(P.p[23][h] + 1e-5f);
        dW_g[i] = P.p[18][i] * A2;
    }
    for (int i = gid; i < HID; i += gstride) ws[OFF_GAM + i] = P.p[24][i];

    if (blockIdx.x == 0) {
        // ---- bias partial sums: thread (part = tid>>5, h = tid&31) ----
        {
            const int h = tid & 31, part = tid >> 5;
            float s = 0.f;
            for (int c = part * 64; c < part * 64 + 64; ++c) {
                float A1 = P.p[2][c] * rsqrtf(P.p[5][c] + 1e-5f);
                float C1 = (P.p[1][c] - P.p[4][c]) * A1 + P.p[3][c];
                s += C1 * P.p[6][(size_t)c * HID + h];
            }
            pse[part][h] = s;
            float sg = 0.f;
            for (int c = part * 18; c < part * 18 + 18; ++c) {
                float A1 = P.p[14][c] * rsqrtf(P.p[17][c] + 1e-5f);
                float C1 = (P.p[13][c] - P.p[16][c]) * A1 + P.p[15][c];
                sg += C1 * P.p[18][(size_t)c * HID + h];
            }
            psg[part][h] = sg;
        }
        __syncthreads();
        if (tid < HID) {
            int h = tid;
            float A2 = P.p[8][h] * rsqrtf(P.p[11][h] + 1e-5f);
            float s = pse[0][h] + pse[1][h] + pse[2][h] + pse[3][h]
                    + pse[4][h] + pse[5][h] + pse[6][h] + pse[7][h];
            ws[OFF_BTE + h] = A2 * (s + P.p[7][h] - P.p[10][h]) + P.p[9][h];
        } else if (tid >= 64 && tid < 64 + HID) {
            int h = tid - 64;
            float A2 = P.p[20][h] * rsqrtf(P.p[23][h] + 1e-5f);
            float s = psg[0][h] + psg[1][h] + psg[2][h] + psg[3][h]
                    + psg[4][h] + psg[5][h] + psg[6][h] + psg[7][h];
            ws[OFF_BTG + h] = A2 * (s + P.p[19][h] - P.p[22][h]) + P.p[21][h];
        }
    }
}

// conv inner: stream 12 b128 chunks of the 47-wide window with 1-deep
// lookahead; per-t FMA order is j (=t+k) ascending == k ascending:
// bit-identical to the scalar version.
__device__ __forceinline__ void conv_stream(const float4* __restrict__ xp4,
                                            const float* __restrict__ w,
                                            float* __restrict__ acc)
{
    float4 cur = xp4[0];
    #pragma unroll
    for (int j4 = 0; j4 < 12; ++j4) {
        float4 nxt = (j4 < 11) ? xp4[j4 + 1] : cur;
        #pragma unroll
        for (int i2 = 0; i2 < 4; ++i2) {
            const int i = j4 * 4 + i2;
            const float xv = (i2 == 0) ? cur.x : (i2 == 1) ? cur.y
                           : (i2 == 2) ? cur.z : cur.w;
            const int tlo = (i - 31 > 0) ? (i - 31) : 0;
            const int thi = (i < 15) ? i : 15;
            #pragma unroll
            for (int t = tlo; t <= thi; ++t)
                acc[t] = fmaf(xv, w[i - t], acc[t]);
        }
        cur = nxt;
    }
}

__device__ __forceinline__ void geo_conv_unit(const float* __restrict__ convW,
                                              const float* __restrict__ xsT,
                                              float* __restrict__ cz,
                                              int c, int th)
{
    float w[KW];
    const float4* wp4 = (const float4*)(convW + c * KW);
    #pragma unroll
    for (int k4 = 0; k4 < 8; ++k4) {
        float4 v = wp4[k4];
        w[4*k4+0]=v.x; w[4*k4+1]=v.y; w[4*k4+2]=v.z; w[4*k4+3]=v.w;
    }
    float acc[16];
    #pragma unroll
    for (int t = 0; t < 16; ++t) acc[t] = 0.f;
    conv_stream((const float4*)(xsT + (c >> 3) * 68 + th * 16), w, acc);
    float4* czp = (float4*)(cz + c * 36 + th * 16);
    czp[0] = make_float4(acc[0],  acc[1],  acc[2],  acc[3]);
    czp[1] = make_float4(acc[4],  acc[5],  acc[6],  acc[7]);
    czp[2] = make_float4(acc[8],  acc[9],  acc[10], acc[11]);
    czp[3] = make_float4(acc[12], acc[13], acc[14], acc[15]);
}

// ============================================================
// Merged path kernel — EXACT r8 form (measured 538 us, VGPR 60,
// FETCH 99 MB, total 674). r9's sv-live-across-dense variant made the
// allocator balloon to 152 VGPR (occupancy 10%, 977 us) without
// spilling: THIRD failed pipelining attempt (r2/r3: scratch demotion;
// r9: reg-bloat). Transient per-phase staging between barriers is the
// only register-safe form for this body — do not re-pipeline.
// ============================================================
__global__ __launch_bounds__(256)
void path_both(const float* __restrict__ xe, const float* __restrict__ xg,
               float* __restrict__ ws)
{
    __shared__ __align__(16) float smem[6408];

    const int b   = blockIdx.y;
    const int tid = threadIdx.x;

    if (blockIdx.x < NT) {
        // ================= EEG =================
        const int t0 = blockIdx.x * TT;
        float* xsT = smem;            // 16*68 = 1088
        float* cz  = smem + 1088;     // 128*36 = 4608
        const float* convW = ws + OFF_CWE;
        const float* dW    = ws + OFF_DWE;
        float* enc         = ws + OFF_ENC;

        const float* xb = xe + (size_t)b * (TLEN * EEGC);

        const int tg = tid & 7, hg = (tid >> 3) & 7, q = tid >> 6;
        const int c_loc = tid & 127, th = tid >> 7;
        float a00=0,a01=0,a02=0,a03=0, a10=0,a11=0,a12=0,a13=0;
        float a20=0,a21=0,a22=0,a23=0, a30=0,a31=0,a32=0,a33=0;

        #pragma unroll 1
        for (int ph = 0; ph < 4; ++ph) {
            if (ph) __syncthreads();
            // ---- stage this phase's 16-channel x-slice (transient regs) ----
            if (tid < 252) {
                const int sj = tid >> 2, sc4 = tid & 3;
                const int st = t0 - 15 + sj;
                float4 sv = make_float4(0.f, 0.f, 0.f, 0.f);
                if (st >= 0 && st < TLEN)
                    sv = *(const float4*)(xb + (size_t)st * EEGC + ph * 16 + sc4 * 4);
                float* p = &xsT[(sc4 * 4) * 68 + sj];
                p[0] = sv.x; p[68] = sv.y; p[136] = sv.z; p[204] = sv.w;
            }
            __syncthreads();
            // ---- conv ----
            {
                const int c   = ph * 128 + c_loc;
                const int chl = c_loc >> 3;
                float w[KW];
                const float4* wp4 = (const float4*)(convW + c * KW);
                #pragma unroll
                for (int k4 = 0; k4 < 8; ++k4) {
                    float4 v = wp4[k4];
                    w[4*k4+0]=v.x; w[4*k4+1]=v.y; w[4*k4+2]=v.z; w[4*k4+3]=v.w;
                }
                float acc[16];
                #pragma unroll
                for (int t = 0; t < 16; ++t) acc[t] = 0.f;
                conv_stream((const float4*)(&xsT[chl * 68 + th * 16]), w, acc);
                float4* czp = (float4*)(cz + c_loc * 36 + th * 16);
                czp[0] = make_float4(acc[0],  acc[1],  acc[2],  acc[3]);
                czp[1] = make_float4(acc[4],  acc[5],  acc[6],  acc[7]);
                czp[2] = make_float4(acc[8],  acc[9],  acc[10], acc[11]);
                czp[3] = make_float4(acc[12], acc[13], acc[14], acc[15]);
            }
            __syncthreads();
            // ---- dense partial ----
            {
                const float* dWh = dW + (size_t)(ph * 128 + q * 32) * HID + hg * 4;
                const float* czb = cz + (q * 32) * 36 + tg * 4;
                float4 wvb[4], cvb[2];
                wvb[0] = *(const float4*)(dWh + 0 * HID);
                wvb[1] = *(const float4*)(dWh + 1 * HID);
                wvb[2] = *(const float4*)(dWh + 2 * HID);
                wvb[3] = *(const float4*)(dWh + 3 * HID);
                cvb[0] = *(const float4*)(czb + 0 * 36);
                cvb[1] = *(const float4*)(czb + 1 * 36);
                #pragma unroll
                for (int ci = 0; ci < 32; ++ci) {
                    float4 cv = cvb[ci & 1];
                    float4 wv = wvb[ci & 3];
                    if (ci + 2 < 32) cvb[ci & 1] = *(const float4*)(czb + (ci + 2) * 36);
                    if (ci + 4 < 32) wvb[ci & 3] = *(const float4*)(dWh + (ci + 4) * HID);
                    a00 = fmaf(cv.x, wv.x, a00); a01 = fmaf(cv.x, wv.y, a01);
                    a02 = fmaf(cv.x, wv.z, a02); a03 = fmaf(cv.x, wv.w, a03);
                    a10 = fmaf(cv.y, wv.x, a10); a11 = fmaf(cv.y, wv.y, a11);
                    a12 = fmaf(cv.y, wv.z, a12); a13 = fmaf(cv.y, wv.w, a13);
                    a20 = fmaf(cv.z, wv.x, a20); a21 = fmaf(cv.z, wv.y, a21);
                    a22 = fmaf(cv.z, wv.z, a22); a23 = fmaf(cv.z, wv.w, a23);
                    a30 = fmaf(cv.w, wv.x, a30); a31 = fmaf(cv.w, wv.y, a31);
                    a32 = fmaf(cv.w, wv.z, a32); a33 = fmaf(cv.w, wv.w, a33);
                }
            }
        }

        // ---- 4-chunk reduction (stash stride 16, XOR group swizzle) ----
        __syncthreads();
        float* stash = cz;   // 256*16 = 4096 floats
        {
            const int s = (tid >> 1) & 3;
            float4* sp = (float4*)(stash + tid * 16);
            sp[s ^ 0] = make_float4(a00,a01,a02,a03);
            sp[s ^ 1] = make_float4(a10,a11,a12,a13);
            sp[s ^ 2] = make_float4(a20,a21,a22,a23);
            sp[s ^ 3] = make_float4(a30,a31,a32,a33);
        }
        __syncthreads();
        {
            const int t = tid >> 3, hq = tid & 7;
            const int pg = (t & 3) ^ (t >> 3);
            float4 v = make_float4(0.f,0.f,0.f,0.f);
            #pragma unroll
            for (int qq = 0; qq < 4; ++qq) {
                const int partner = qq * 64 + hq * 8 + (t >> 2);
                float4 s = *(const float4*)(stash + partner * 16 + pg * 4);
                v.x += s.x; v.y += s.y; v.z += s.z; v.w += s.w;
            }
            float4 bias = *(const float4*)(ws + OFF_BTE + hq * 4);
            v.x = fmaxf(v.x + bias.x, 0.f);
            v.y = fmaxf(v.y + bias.y, 0.f);
            v.z = fmaxf(v.z + bias.z, 0.f);
            v.w = fmaxf(v.w + bias.w, 0.f);
            *(float4*)(enc + ((size_t)(b * TLEN + t0 + t)) * HID + hq * 4) = v;
        }
    } else {
        // ================= GEO =================
        const int t0 = (blockIdx.x - NT) * TT;
        float* xsT = smem;            // 18*68 = 1224
        float* cz  = smem + 1224;     // 144*36 = 5184
        const float* convW = ws + OFF_CWG;
        const float* dW    = ws + OFF_DWG;
        float* mod         = ws + OFF_MOD;

        const float* xb = xg + (size_t)b * (TLEN * GEOC);
        for (int i = tid; i < 63 * GEOC; i += 256) {
            int j = i / GEOC, ch = i - j * GEOC;
            int t = t0 - 15 + j;
            xsT[ch * 68 + j] = (t >= 0 && t < TLEN) ? xb[(size_t)t * GEOC + ch] : 0.f;
        }
        __syncthreads();

        geo_conv_unit(convW, xsT, cz, tid >> 1, tid & 1);
        if (tid < 32)
            geo_conv_unit(convW, xsT, cz, 128 + (tid >> 1), tid & 1);
        __syncthreads();

        const int tg = tid & 7, hg = (tid >> 3) & 7, q = tid >> 6;
        float a00=0,a01=0,a02=0,a03=0, a10=0,a11=0,a12=0,a13=0;
        float a20=0,a21=0,a22=0,a23=0, a30=0,a31=0,a32=0,a33=0;
        {
            const float* dWh = dW + (size_t)(q * 36) * HID + hg * 4;
            const float* czb = cz + (q * 36) * 36 + tg * 4;
            #pragma unroll 2
            for (int ci = 0; ci < 36; ++ci) {
                float4 cv = *(const float4*)(czb + ci * 36);
                float4 wv = *(const float4*)(dWh + ci * HID);
                a00 = fmaf(cv.x, wv.x, a00); a01 = fmaf(cv.x, wv.y, a01);
                a02 = fmaf(cv.x, wv.z, a02); a03 = fmaf(cv.x, wv.w, a03);
                a10 = fmaf(cv.y, wv.x, a10); a11 = fmaf(cv.y, wv.y, a11);
                a12 = fmaf(cv.y, wv.z, a12); a13 = fmaf(cv.y, wv.w, a13);
                a20 = fmaf(cv.z, wv.x, a20); a21 = fmaf(cv.z, wv.y, a21);
                a22 = fmaf(cv.z, wv.z, a22); a23 = fmaf(cv.z, wv.w, a23);
                a30 = fmaf(cv.w, wv.x, a30); a31 = fmaf(cv.w, wv.y, a31);
                a32 = fmaf(cv.w, wv.z, a32); a33 = fmaf(cv.w, wv.w, a33);
            }
        }
        __syncthreads();
        float* stash = cz;
        {
            float4* sp = (float4*)(stash + tid * 20);
            sp[0] = make_float4(a00,a01,a02,a03);
            sp[1] = make_float4(a10,a11,a12,a13);
            sp[2] = make_float4(a20,a21,a22,a23);
            sp[3] = make_float4(a30,a31,a32,a33);
        }
        __syncthreads();
        {
            const int t = tid >> 3, hq = tid & 7;
            float4 v = make_float4(0.f,0.f,0.f,0.f);
            #pragma unroll
            for (int qq = 0; qq < 4; ++qq) {
                const int partner = qq * 64 + hq * 8 + (t >> 2);
                float4 s = *(const float4*)(stash + partner * 20 + (t & 3) * 4);
                v.x += s.x; v.y += s.y; v.z += s.z; v.w += s.w;
            }
            float4 bias = *(const float4*)(ws + OFF_BTG + hq * 4);
            v.x = 1.f / (1.f + expf(-(v.x + bias.x)));
            v.y = 1.f / (1.f + expf(-(v.y + bias.y)));
            v.z = 1.f / (1.f + expf(-(v.z + bias.z)));
            v.w = 1.f / (1.f + expf(-(v.w + bias.w)));
            *(float4*)(mod + ((size_t)(b * TLEN + t0 + t)) * HID + hq * 4) = v;
        }
    }
}

// ============================================================
// Fused scan+head (r7/r8 form). Unchanged.
// ============================================================
#define SSTEP(CE, CG) { \
    const float ce = (CE), cg = (CG); \
    m1 = 0.9f * m1 + ce; float s1 = ((m1 - 0.7f) >= 0.f) ? 1.f : 0.f; m1 = m1 * (1.f - s1); \
    m2 = 0.8f * m2 + ce; float s2 = ((m2 - 0.5f) >= 0.f) ? 1.f : 0.f; m2 = m2 * (1.f - s2); \
    m3 = 0.6f * m3 + ce; float s3 = ((m3 - 0.3f) >= 0.f) ? 1.f : 0.f; m3 = m3 * (1.f - s3); \
    const float hr = (s1 + s2 + s3) / 3.0f; \
    eta = 0.36f * eta + 0.64f * prev; \
    const float theta = 0.5f + 1.8f * eta - g * cg; \
    ma = 0.8f * ma + hr; \
    const float sa = ((ma - theta) >= 0.f) ? 1.f : 0.f; \
    ma = ma * (1.f - sa); \
    mli = 0.9f * mli + sa; \
    prev = sa; }

__global__ __launch_bounds__(128) void scan_head_kernel(
    float* __restrict__ ws,
    const float* __restrict__ f1w, const float* __restrict__ f1b,
    const float* __restrict__ f2w, const float* __restrict__ f2b,
    float* __restrict__ out)
{
    __shared__ __align__(16) float dps[4][320];
    __shared__ float act[4][128];
    const int tid = threadIdx.x;
    const int grp = tid >> 5, h = tid & 31;
    const int b = blockIdx.x * 4 + grp;

    {
        const float g = ws[OFF_GAM + h];
        const float* pe = ws + OFF_ENC + (size_t)b * TLEN * HID + h;
        const float* pg = ws + OFF_MOD + (size_t)b * TLEN * HID + h;
        float* dpp = &dps[grp][h * 10];

        float m1 = 0.f, m2 = 0.f, m3 = 0.f, ma = 0.f, eta = 0.f, mli = 0.f, prev = 0.f;
        float acc_lo = 0.f, acc_hi = 0.f;
        float ceA[16], cgA[16], ceB[16], cgB[16];

        #pragma unroll
        for (int i = 0; i < 16; ++i) { ceA[i] = pe[i * HID]; cgA[i] = pg[i * HID]; }

        #pragma unroll 1
        for (int ch = 0; ch < 20; ch += 2) {
            const int baseB = (ch + 1) * 16;
            #pragma unroll
            for (int i = 0; i < 16; ++i) {
                ceB[i] = pe[(baseB + i) * HID];
                cgB[i] = pg[(baseB + i) * HID];
            }
            #pragma unroll
            for (int i = 0; i < 16; ++i) {
                SSTEP(ceA[i], cgA[i]);
                acc_lo += mli;
            }
            if (ch + 2 < 20) {
                const int baseA = (ch + 2) * 16;
                #pragma unroll
                for (int i = 0; i < 16; ++i) {
                    ceA[i] = pe[(baseA + i) * HID];
                    cgA[i] = pg[(baseA + i) * HID];
                }
            }
            #pragma unroll
            for (int i = 0; i < 16; ++i) {
                SSTEP(ceB[i], cgB[i]);
                acc_hi += mli;
            }
            dpp[ch >> 1] = acc_hi * (1.f / 16.f) - acc_lo * (1.f / 16.f);
            acc_lo = 0.f; acc_hi = 0.f;
        }
    }
    __syncthreads();

    {
        const int j = tid;
        #pragma unroll 1
        for (int gb = 0; gb < 4; ++gb) {
            const float* dpb = dps[gb];
            float a0 = 0.f, a1 = 0.f, a2 = 0.f, a3 = 0.f;
            #pragma unroll 4
            for (int i = 0; i < 320; i += 4) {
                a0 = fmaf(dpb[i + 0], f1w[(i + 0) * 128 + j], a0);
                a1 = fmaf(dpb[i + 1], f1w[(i + 1) * 128 + j], a1);
                a2 = fmaf(dpb[i + 2], f1w[(i + 2) * 128 + j], a2);
                a3 = fmaf(dpb[i + 3], f1w[(i + 3) * 128 + j], a3);
            }
            float a = f1b[j] + ((a0 + a1) + (a2 + a3));
            act[gb][j] = (a > 0.f) ? a : expm1f(a);   // ELU, alpha=1
        }
    }
    __syncthreads();

    if (tid < 16) {
        const int gb = tid >> 2, j = tid & 3;
        float o = f2b[j];
        for (int jj = 0; jj < 128; ++jj)
            o = fmaf(act[gb][jj], f2w[jj * 4 + j], o);
        out[(blockIdx.x * 4 + gb) * 4 + j] = o;
    }
}

// ============================================================
extern "C" void kernel_launch(void* const* d_in, const int* in_sizes, int n_in,
                              void* d_out, int out_size, void* d_ws, size_t ws_size,
                              hipStream_t stream)
{
    float* ws = (float*)d_ws;

    P29 P;
    for (int k = 0; k < 29; ++k) P.p[k] = (const float*)d_in[k + 2];
    prep_kernel<<<33, 256, 0, stream>>>(P, ws);

    path_both<<<dim3(2 * NT, BSZ), 256, 0, stream>>>(
        (const float*)d_in[0], (const float*)d_in[1], ws);

    scan_head_kernel<<<BSZ / 4, 128, 0, stream>>>(
        ws, (const float*)d_in[27], (const float*)d_in[28],
        (const float*)d_in[29], (const float*)d_in[30], (float*)d_out);
}

// Round 11
// 687.186 us; speedup vs baseline: 1.6113x; 1.0281x over previous
//
#include <hip/hip_runtime.h>
#include <hip/hip_bf16.h>
#include <math.h>

#define BSZ   1024
#define TLEN  320
#define EEGC  64
#define GEOC  18
#define ECH   512    // 64*8
#define GCH   144    // 18*8
#define HID   32
#define KW    32
#define TT    32
#define NT    (TLEN/TT)   // 10
#define BPB   2           // b-values per path block (dispatch-rate test)

// ---- workspace layout (float offsets) ----
#define OFF_ENC  0
#define OFF_MOD  (OFF_ENC + BSZ*TLEN*HID)
#define OFF_DP   (OFF_MOD + BSZ*TLEN*HID)
#define OFF_CWE  (OFF_DP + BSZ*HID*10)           // conv weights eeg [c][k] (A1-folded)
#define OFF_CWG  (OFF_CWE + ECH*KW)
#define OFF_DWE  (OFF_CWG + GCH*KW)              // dense weights eeg [c][h] (A2-folded)
#define OFF_DWG  (OFF_DWE + ECH*HID)
#define OFF_BTE  (OFF_DWG + GCH*HID)
#define OFF_BTG  (OFF_BTE + HID)
#define OFF_GAM  (OFF_BTG + HID)

struct P29 { const float* p[29]; };
// 0 ecw 1 ecb 2 e1s 3 e1b 4 e1m 5 e1v 6 edw 7 edb 8 e2s 9 e2b 10 e2m 11 e2v
// 12 gcw 13 gcb 14 g1s 15 g1b 16 g1m 17 g1v 18 gdw 19 gdb 20 g2s 21 g2b 22 g2m 23 g2v
// 24 gamma 25 fc1w 26 fc1b 27 fc2w 28 fc2b

// ============================================================
// prep v3 (r8 form). Unchanged.
// ============================================================
__global__ __launch_bounds__(256) void prep_kernel(P29 P, float* __restrict__ ws)
{
    __shared__ float pse[8][32];
    __shared__ float psg[8][32];
    const int tid = threadIdx.x;
    const int gid = blockIdx.x * 256 + tid;
    const int gstride = 33 * 256;
    float* convW_e = ws + OFF_CWE;
    float* convW_g = ws + OFF_CWG;
    float* dW_e    = ws + OFF_DWE;
    float* dW_g    = ws + OFF_DWG;

    for (int i = gid; i < ECH * KW; i += gstride) {
        int c = i >> 5, k = i & 31;
        float A1 = P.p[2][c] * rsqrtf(P.p[5][c] + 1e-5f);
        convW_e[c * KW + k] = P.p[0][(size_t)k * ECH + c] * A1;
    }
    for (int i = gid; i < GCH * KW; i += gstride) {
        int c = i >> 5, k = i & 31;
        float A1 = P.p[14][c] * rsqrtf(P.p[17][c] + 1e-5f);
        convW_g[c * KW + k] = P.p[12][(size_t)k * GCH + c] * A1;
    }
    for (int i = gid; i < ECH * HID; i += gstride) {
        int h = i & 31;
        float A2 = P.p[8][h] * rsqrtf(P.p[11][h] + 1e-5f);
        dW_e[i] = P.p[6][i] * A2;
    }
    for (int i = gid; i < GCH * HID; i += gstride) {
        int h = i & 31;
        float A2 = P.p[20][h] * rsqrtf(P.p[23][h] + 1e-5f);
        dW_g[i] = P.p[18][i] * A2;
    }
    for (int i = gid; i < HID; i += gstride) ws[OFF_GAM + i] = P.p[24][i];

    if (blockIdx.x == 0) {
        {
            const int h = tid & 31, part = tid >> 5;
            float s = 0.f;
            for (int c = part * 64; c < part * 64 + 64; ++c) {
                float A1 = P.p[2][c] * rsqrtf(P.p[5][c] + 1e-5f);
                float C1 = (P.p[1][c] - P.p[4][c]) * A1 + P.p[3][c];
                s += C1 * P.p[6][(size_t)c * HID + h];
            }
            pse[part][h] = s;
            float sg = 0.f;
            for (int c = part * 18; c < part * 18 + 18; ++c) {
                float A1 = P.p[14][c] * rsqrtf(P.p[17][c] + 1e-5f);
                float C1 = (P.p[13][c] - P.p[16][c]) * A1 + P.p[15][c];
                sg += C1 * P.p[18][(size_t)c * HID + h];
            }
            psg[part][h] = sg;
        }
        __syncthreads();
        if (tid < HID) {
            int h = tid;
            float A2 = P.p[8][h] * rsqrtf(P.p[11][h] + 1e-5f);
            float s = pse[0][h] + pse[1][h] + pse[2][h] + pse[3][h]
                    + pse[4][h] + pse[5][h] + pse[6][h] + pse[7][h];
            ws[OFF_BTE + h] = A2 * (s + P.p[7][h] - P.p[10][h]) + P.p[9][h];
        } else if (tid >= 64 && tid < 64 + HID) {
            int h = tid - 64;
            float A2 = P.p[20][h] * rsqrtf(P.p[23][h] + 1e-5f);
            float s = psg[0][h] + psg[1][h] + psg[2][h] + psg[3][h]
                    + psg[4][h] + psg[5][h] + psg[6][h] + psg[7][h];
            ws[OFF_BTG + h] = A2 * (s + P.p[19][h] - P.p[22][h]) + P.p[21][h];
        }
    }
}

// conv inner: stream 12 b128 chunks of the 47-wide window with 1-deep
// lookahead; per-t FMA order is j (=t+k) ascending == k ascending:
// bit-identical to the scalar version.
__device__ __forceinline__ void conv_stream(const float4* __restrict__ xp4,
                                            const float* __restrict__ w,
                                            float* __restrict__ acc)
{
    float4 cur = xp4[0];
    #pragma unroll
    for (int j4 = 0; j4 < 12; ++j4) {
        float4 nxt = (j4 < 11) ? xp4[j4 + 1] : cur;
        #pragma unroll
        for (int i2 = 0; i2 < 4; ++i2) {
            const int i = j4 * 4 + i2;
            const float xv = (i2 == 0) ? cur.x : (i2 == 1) ? cur.y
                           : (i2 == 2) ? cur.z : cur.w;
            const int tlo = (i - 31 > 0) ? (i - 31) : 0;
            const int thi = (i < 15) ? i : 15;
            #pragma unroll
            for (int t = tlo; t <= thi; ++t)
                acc[t] = fmaf(xv, w[i - t], acc[t]);
        }
        cur = nxt;
    }
}

__device__ __forceinline__ void geo_conv_unit(const float* __restrict__ convW,
                                              const float* __restrict__ xsT,
                                              float* __restrict__ cz,
                                              int c, int th)
{
    float w[KW];
    const float4* wp4 = (const float4*)(convW + c * KW);
    #pragma unroll
    for (int k4 = 0; k4 < 8; ++k4) {
        float4 v = wp4[k4];
        w[4*k4+0]=v.x; w[4*k4+1]=v.y; w[4*k4+2]=v.z; w[4*k4+3]=v.w;
    }
    float acc[16];
    #pragma unroll
    for (int t = 0; t < 16; ++t) acc[t] = 0.f;
    conv_stream((const float4*)(xsT + (c >> 3) * 68 + th * 16), w, acc);
    float4* czp = (float4*)(cz + c * 36 + th * 16);
    czp[0] = make_float4(acc[0],  acc[1],  acc[2],  acc[3]);
    czp[1] = make_float4(acc[4],  acc[5],  acc[6],  acc[7]);
    czp[2] = make_float4(acc[8],  acc[9],  acc[10], acc[11]);
    czp[3] = make_float4(acc[12], acc[13], acc[14], acc[15]);
}

// ============================================================
// Merged path kernel — r8 body, wrapped in a BPB=2 loop over
// consecutive b values (grid y halved: 10240 blocks total, was
// 20480). Tests the dispatch-rate hypothesis for the ~3-block/CU
// residency plateau: per-work-unit instruction stream is identical;
// only WG count halves. All per-bb state transient (accumulators
// declared inside the loop — r2/r3/r9 cross-region-liveness lesson).
// Race check at the bb seam: bb0's stash reads target czs; bb1's
// first write targets xsT (disjoint); bb1's cz writes happen after a
// barrier all threads pass only post-stash-read. Safe with existing
// barriers. Tripwires: FETCH >> 99 MB (spill) / VGPR >> 64 (bloat).
// ============================================================
__global__ __launch_bounds__(256)
void path_both(const float* __restrict__ xe, const float* __restrict__ xg,
               float* __restrict__ ws)
{
    __shared__ __align__(16) float smem[6408];

    const int by  = blockIdx.y;
    const int tid = threadIdx.x;

    if (blockIdx.x < NT) {
        // ================= EEG =================
        const int t0 = blockIdx.x * TT;
        float* xsT = smem;            // 16*68 = 1088
        float* cz  = smem + 1088;     // 128*36 = 4608
        const float* convW = ws + OFF_CWE;
        const float* dW    = ws + OFF_DWE;
        float* enc         = ws + OFF_ENC;

        const int tg = tid & 7, hg = (tid >> 3) & 7, q = tid >> 6;
        const int c_loc = tid & 127, th = tid >> 7;

        #pragma unroll 1
        for (int bb = 0; bb < BPB; ++bb) {
            const int b = by * BPB + bb;
            const float* xb = xe + (size_t)b * (TLEN * EEGC);

            float a00=0,a01=0,a02=0,a03=0, a10=0,a11=0,a12=0,a13=0;
            float a20=0,a21=0,a22=0,a23=0, a30=0,a31=0,a32=0,a33=0;

            #pragma unroll 1
            for (int ph = 0; ph < 4; ++ph) {
                if (ph) __syncthreads();
                // ---- stage this phase's 16-channel x-slice (transient) ----
                if (tid < 252) {
                    const int sj = tid >> 2, sc4 = tid & 3;
                    const int st = t0 - 15 + sj;
                    float4 sv = make_float4(0.f, 0.f, 0.f, 0.f);
                    if (st >= 0 && st < TLEN)
                        sv = *(const float4*)(xb + (size_t)st * EEGC + ph * 16 + sc4 * 4);
                    float* p = &xsT[(sc4 * 4) * 68 + sj];
                    p[0] = sv.x; p[68] = sv.y; p[136] = sv.z; p[204] = sv.w;
                }
                __syncthreads();
                // ---- conv ----
                {
                    const int c   = ph * 128 + c_loc;
                    const int chl = c_loc >> 3;
                    float w[KW];
                    const float4* wp4 = (const float4*)(convW + c * KW);
                    #pragma unroll
                    for (int k4 = 0; k4 < 8; ++k4) {
                        float4 v = wp4[k4];
                        w[4*k4+0]=v.x; w[4*k4+1]=v.y; w[4*k4+2]=v.z; w[4*k4+3]=v.w;
                    }
                    float acc[16];
                    #pragma unroll
                    for (int t = 0; t < 16; ++t) acc[t] = 0.f;
                    conv_stream((const float4*)(&xsT[chl * 68 + th * 16]), w, acc);
                    float4* czp = (float4*)(cz + c_loc * 36 + th * 16);
                    czp[0] = make_float4(acc[0],  acc[1],  acc[2],  acc[3]);
                    czp[1] = make_float4(acc[4],  acc[5],  acc[6],  acc[7]);
                    czp[2] = make_float4(acc[8],  acc[9],  acc[10], acc[11]);
                    czp[3] = make_float4(acc[12], acc[13], acc[14], acc[15]);
                }
                __syncthreads();
                // ---- dense partial ----
                {
                    const float* dWh = dW + (size_t)(ph * 128 + q * 32) * HID + hg * 4;
                    const float* czb = cz + (q * 32) * 36 + tg * 4;
                    float4 wvb[4], cvb[2];
                    wvb[0] = *(const float4*)(dWh + 0 * HID);
                    wvb[1] = *(const float4*)(dWh + 1 * HID);
                    wvb[2] = *(const float4*)(dWh + 2 * HID);
                    wvb[3] = *(const float4*)(dWh + 3 * HID);
                    cvb[0] = *(const float4*)(czb + 0 * 36);
                    cvb[1] = *(const float4*)(czb + 1 * 36);
                    #pragma unroll
                    for (int ci = 0; ci < 32; ++ci) {
                        float4 cv = cvb[ci & 1];
                        float4 wv = wvb[ci & 3];
                        if (ci + 2 < 32) cvb[ci & 1] = *(const float4*)(czb + (ci + 2) * 36);
                        if (ci + 4 < 32) wvb[ci & 3] = *(const float4*)(dWh + (ci + 4) * HID);
                        a00 = fmaf(cv.x, wv.x, a00); a01 = fmaf(cv.x, wv.y, a01);
                        a02 = fmaf(cv.x, wv.z, a02); a03 = fmaf(cv.x, wv.w, a03);
                        a10 = fmaf(cv.y, wv.x, a10); a11 = fmaf(cv.y, wv.y, a11);
                        a12 = fmaf(cv.y, wv.z, a12); a13 = fmaf(cv.y, wv.w, a13);
                        a20 = fmaf(cv.z, wv.x, a20); a21 = fmaf(cv.z, wv.y, a21);
                        a22 = fmaf(cv.z, wv.z, a22); a23 = fmaf(cv.z, wv.w, a23);
                        a30 = fmaf(cv.w, wv.x, a30); a31 = fmaf(cv.w, wv.y, a31);
                        a32 = fmaf(cv.w, wv.z, a32); a33 = fmaf(cv.w, wv.w, a33);
                    }
                }
            }

            // ---- 4-chunk reduction (stash stride 16, XOR group swizzle) ----
            __syncthreads();
            float* stash = cz;   // 256*16 = 4096 floats
            {
                const int s = (tid >> 1) & 3;
                float4* sp = (float4*)(stash + tid * 16);
                sp[s ^ 0] = make_float4(a00,a01,a02,a03);
                sp[s ^ 1] = make_float4(a10,a11,a12,a13);
                sp[s ^ 2] = make_float4(a20,a21,a22,a23);
                sp[s ^ 3] = make_float4(a30,a31,a32,a33);
            }
            __syncthreads();
            {
                const int t = tid >> 3, hq = tid & 7;
                const int pg = (t & 3) ^ (t >> 3);
                float4 v = make_float4(0.f,0.f,0.f,0.f);
                #pragma unroll
                for (int qq = 0; qq < 4; ++qq) {
                    const int partner = qq * 64 + hq * 8 + (t >> 2);
                    float4 s = *(const float4*)(stash + partner * 16 + pg * 4);
                    v.x += s.x; v.y += s.y; v.z += s.z; v.w += s.w;
                }
                float4 bias = *(const float4*)(ws + OFF_BTE + hq * 4);
                v.x = fmaxf(v.x + bias.x, 0.f);
                v.y = fmaxf(v.y + bias.y, 0.f);
                v.z = fmaxf(v.z + bias.z, 0.f);
                v.w = fmaxf(v.w + bias.w, 0.f);
                *(float4*)(enc + ((size_t)(b * TLEN + t0 + t)) * HID + hq * 4) = v;
            }
        }
    } else {
        // ================= GEO =================
        const int t0 = (blockIdx.x - NT) * TT;
        float* xsT = smem;            // 18*68 = 1224
        float* cz  = smem + 1224;     // 144*36 = 5184
        const float* convW = ws + OFF_CWG;
        const float* dW    = ws + OFF_DWG;
        float* mod         = ws + OFF_MOD;

        const int tg = tid & 7, hg = (tid >> 3) & 7, q = tid >> 6;

        #pragma unroll 1
        for (int bb = 0; bb < BPB; ++bb) {
            const int b = by * BPB + bb;
            const float* xb = xg + (size_t)b * (TLEN * GEOC);

            if (bb) __syncthreads();   // prev stash reads done before xsT/cz reuse
            for (int i = tid; i < 63 * GEOC; i += 256) {
                int j = i / GEOC, ch = i - j * GEOC;
                int t = t0 - 15 + j;
                xsT[ch * 68 + j] = (t >= 0 && t < TLEN) ? xb[(size_t)t * GEOC + ch] : 0.f;
            }
            __syncthreads();

            geo_conv_unit(convW, xsT, cz, tid >> 1, tid & 1);
            if (tid < 32)
                geo_conv_unit(convW, xsT, cz, 128 + (tid >> 1), tid & 1);
            __syncthreads();

            float a00=0,a01=0,a02=0,a03=0, a10=0,a11=0,a12=0,a13=0;
            float a20=0,a21=0,a22=0,a23=0, a30=0,a31=0,a32=0,a33=0;
            {
                const float* dWh = dW + (size_t)(q * 36) * HID + hg * 4;
                const float* czb = cz + (q * 36) * 36 + tg * 4;
                #pragma unroll 2
                for (int ci = 0; ci < 36; ++ci) {
                    float4 cv = *(const float4*)(czb + ci * 36);
                    float4 wv = *(const float4*)(dWh + ci * HID);
                    a00 = fmaf(cv.x, wv.x, a00); a01 = fmaf(cv.x, wv.y, a01);
                    a02 = fmaf(cv.x, wv.z, a02); a03 = fmaf(cv.x, wv.w, a03);
                    a10 = fmaf(cv.y, wv.x, a10); a11 = fmaf(cv.y, wv.y, a11);
                    a12 = fmaf(cv.y, wv.z, a12); a13 = fmaf(cv.y, wv.w, a13);
                    a20 = fmaf(cv.z, wv.x, a20); a21 = fmaf(cv.z, wv.y, a21);
                    a22 = fmaf(cv.z, wv.z, a22); a23 = fmaf(cv.z, wv.w, a23);
                    a30 = fmaf(cv.w, wv.x, a30); a31 = fmaf(cv.w, wv.y, a31);
                    a32 = fmaf(cv.w, wv.z, a32); a33 = fmaf(cv.w, wv.w, a33);
                }
            }
            __syncthreads();
            float* stash = cz;
            {
                float4* sp = (float4*)(stash + tid * 20);
                sp[0] = make_float4(a00,a01,a02,a03);
                sp[1] = make_float4(a10,a11,a12,a13);
                sp[2] = make_float4(a20,a21,a22,a23);
                sp[3] = make_float4(a30,a31,a32,a33);
            }
            __syncthreads();
            {
                const int t = tid >> 3, hq = tid & 7;
                float4 v = make_float4(0.f,0.f,0.f,0.f);
                #pragma unroll
                for (int qq = 0; qq < 4; ++qq) {
                    const int partner = qq * 64 + hq * 8 + (t >> 2);
                    float4 s = *(const float4*)(stash + partner * 20 + (t & 3) * 4);
                    v.x += s.x; v.y += s.y; v.z += s.z; v.w += s.w;
                }
                float4 bias = *(const float4*)(ws + OFF_BTG + hq * 4);
                v.x = 1.f / (1.f + expf(-(v.x + bias.x)));
                v.y = 1.f / (1.f + expf(-(v.y + bias.y)));
                v.z = 1.f / (1.f + expf(-(v.z + bias.z)));
                v.w = 1.f / (1.f + expf(-(v.w + bias.w)));
                *(float4*)(mod + ((size_t)(b * TLEN + t0 + t)) * HID + hq * 4) = v;
            }
        }
    }
}

// ============================================================
// Fused scan+head (r7/r8 form). Unchanged.
// ============================================================
#define SSTEP(CE, CG) { \
    const float ce = (CE), cg = (CG); \
    m1 = 0.9f * m1 + ce; float s1 = ((m1 - 0.7f) >= 0.f) ? 1.f : 0.f; m1 = m1 * (1.f - s1); \
    m2 = 0.8f * m2 + ce; float s2 = ((m2 - 0.5f) >= 0.f) ? 1.f : 0.f; m2 = m2 * (1.f - s2); \
    m3 = 0.6f * m3 + ce; float s3 = ((m3 - 0.3f) >= 0.f) ? 1.f : 0.f; m3 = m3 * (1.f - s3); \
    const float hr = (s1 + s2 + s3) / 3.0f; \
    eta = 0.36f * eta + 0.64f * prev; \
    const float theta = 0.5f + 1.8f * eta - g * cg; \
    ma = 0.8f * ma + hr; \
    const float sa = ((ma - theta) >= 0.f) ? 1.f : 0.f; \
    ma = ma * (1.f - sa); \
    mli = 0.9f * mli + sa; \
    prev = sa; }

__global__ __launch_bounds__(128) void scan_head_kernel(
    float* __restrict__ ws,
    const float* __restrict__ f1w, const float* __restrict__ f1b,
    const float* __restrict__ f2w, const float* __restrict__ f2b,
    float* __restrict__ out)
{
    __shared__ __align__(16) float dps[4][320];
    __shared__ float act[4][128];
    const int tid = threadIdx.x;
    const int grp = tid >> 5, h = tid & 31;
    const int b = blockIdx.x * 4 + grp;

    {
        const float g = ws[OFF_GAM + h];
        const float* pe = ws + OFF_ENC + (size_t)b * TLEN * HID + h;
        const float* pg = ws + OFF_MOD + (size_t)b * TLEN * HID + h;
        float* dpp = &dps[grp][h * 10];

        float m1 = 0.f, m2 = 0.f, m3 = 0.f, ma = 0.f, eta = 0.f, mli = 0.f, prev = 0.f;
        float acc_lo = 0.f, acc_hi = 0.f;
        float ceA[16], cgA[16], ceB[16], cgB[16];

        #pragma unroll
        for (int i = 0; i < 16; ++i) { ceA[i] = pe[i * HID]; cgA[i] = pg[i * HID]; }

        #pragma unroll 1
        for (int ch = 0; ch < 20; ch += 2) {
            const int baseB = (ch + 1) * 16;
            #pragma unroll
            for (int i = 0; i < 16; ++i) {
                ceB[i] = pe[(baseB + i) * HID];
                cgB[i] = pg[(baseB + i) * HID];
            }
            #pragma unroll
            for (int i = 0; i < 16; ++i) {
                SSTEP(ceA[i], cgA[i]);
                acc_lo += mli;
            }
            if (ch + 2 < 20) {
                const int baseA = (ch + 2) * 16;
                #pragma unroll
                for (int i = 0; i < 16; ++i) {
                    ceA[i] = pe[(baseA + i) * HID];
                    cgA[i] = pg[(baseA + i) * HID];
                }
            }
            #pragma unroll
            for (int i = 0; i < 16; ++i) {
                SSTEP(ceB[i], cgB[i]);
                acc_hi += mli;
            }
            dpp[ch >> 1] = acc_hi * (1.f / 16.f) - acc_lo * (1.f / 16.f);
            acc_lo = 0.f; acc_hi = 0.f;
        }
    }
    __syncthreads();

    {
        const int j = tid;
        #pragma unroll 1
        for (int gb = 0; gb < 4; ++gb) {
            const float* dpb = dps[gb];
            float a0 = 0.f, a1 = 0.f, a2 = 0.f, a3 = 0.f;
            #pragma unroll 4
            for (int i = 0; i < 320; i += 4) {
                a0 = fmaf(dpb[i + 0], f1w[(i + 0) * 128 + j], a0);
                a1 = fmaf(dpb[i + 1], f1w[(i + 1) * 128 + j], a1);
                a2 = fmaf(dpb[i + 2], f1w[(i + 2) * 128 + j], a2);
                a3 = fmaf(dpb[i + 3], f1w[(i + 3) * 128 + j], a3);
            }
            float a = f1b[j] + ((a0 + a1) + (a2 + a3));
            act[gb][j] = (a > 0.f) ? a : expm1f(a);   // ELU, alpha=1
        }
    }
    __syncthreads();

    if (tid < 16) {
        const int gb = tid >> 2, j = tid & 3;
        float o = f2b[j];
        for (int jj = 0; jj < 128; ++jj)
            o = fmaf(act[gb][jj], f2w[jj * 4 + j], o);
        out[(blockIdx.x * 4 + gb) * 4 + j] = o;
    }
}

// ============================================================
extern "C" void kernel_launch(void* const* d_in, const int* in_sizes, int n_in,
                              void* d_out, int out_size, void* d_ws, size_t ws_size,
                              hipStream_t stream)
{
    float* ws = (float*)d_ws;

    P29 P;
    for (int k = 0; k < 29; ++k) P.p[k] = (const float*)d_in[k + 2];
    prep_kernel<<<33, 256, 0, stream>>>(P, ws);

    path_both<<<dim3(2 * NT, BSZ / BPB), 256, 0, stream>>>(
        (const float*)d_in[0], (const float*)d_in[1], ws);

    scan_head_kernel<<<BSZ / 4, 128, 0, stream>>>(
        ws, (const float*)d_in[27], (const float*)d_in[28],
        (const float*)d_in[29], (const float*)d_in[30], (float*)d_out);
}